// Round 13
// baseline (194.579 us; speedup 1.0000x reference)
//
#include <hip/hip_runtime.h>
#include <hip/hip_bf16.h>

#define F 128
// CAP=32 u16 entries => each node's bucket is exactly ONE 64B cache line.
// E[deg]=12, P(deg>=32)~1.2e-6; overflow list keeps full correctness anyway.
// NOTE: u16 src indices require n <= 65535 (n=50000 here).
#define CAP 32
#define NF 2048  // fill blocks in K1 (multiple of 8): 256 scan-groups x 8 col-classes

typedef __bf16 bf16x8 __attribute__((ext_vector_type(8)));
typedef float f32x4 __attribute__((ext_vector_type(4)));

static __device__ __forceinline__ unsigned int f2bfbits(float f) {
  unsigned int u = __float_as_uint(f);
  return (u + 0x7fffu + ((u >> 16) & 1u)) >> 16;
}

// ---- K0: lstm (blocks 0..31) || zero deg+ovf_cnt (blocks 32..) -----------
__global__ __launch_bounds__(256) void lstm_zero_kernel(
    const float* __restrict__ W0, const float* __restrict__ w_ih,
    const float* __restrict__ b_ih, const float* __restrict__ b_hh,
    unsigned short* __restrict__ Wt, int* __restrict__ deg,
    int* __restrict__ ovf_cnt, int n) {
  __shared__ __align__(16) float srow[4][F];  // 2 KB
  __shared__ float sg[4][4 * F];              // 8 KB
  int b = blockIdx.x, t = threadIdx.x;
  if (b < 32) {
    int r0 = b * 4;
    for (int i = t; i < 4 * F; i += 256)
      srow[i >> 7][i & 127] = W0[(size_t)(r0 + (i >> 7)) * F + (i & 127)];
    __syncthreads();
#pragma unroll
    for (int half = 0; half < 2; half++) {
      int gc = t + half * 256;  // gate col 0..511
      float acc[4] = {0.f, 0.f, 0.f, 0.f};
      const float4* wv4 = (const float4*)(w_ih + (size_t)gc * F);
#pragma unroll 4
      for (int k4 = 0; k4 < F / 4; k4++) {
        float4 w = wv4[k4];
#pragma unroll
        for (int i = 0; i < 4; i++) {
          float4 s = *(const float4*)&srow[i][k4 * 4];
          acc[i] = fmaf(s.x, w.x, fmaf(s.y, w.y, fmaf(s.z, w.z, fmaf(s.w, w.w, acc[i]))));
        }
      }
      float bias = b_ih[gc] + b_hh[gc];
#pragma unroll
      for (int i = 0; i < 4; i++) sg[i][gc] = acc[i] + bias;
    }
    __syncthreads();
#pragma unroll
    for (int half = 0; half < 2; half++) {
      int idx2 = t + half * 256;  // 0..511 = 4 rows x 128 cols
      int rr = idx2 >> 7, c = idx2 & 127;
      float gi = sg[rr][c], gg = sg[rr][c + 2 * F], go = sg[rr][c + 3 * F];
      float si = 1.f / (1.f + expf(-gi));
      float so = 1.f / (1.f + expf(-go));
      float cc2 = si * tanhf(gg);
      // Wt[n][k] = bf16(W[k][n]), k = r0+rr, n = c
      Wt[(size_t)c * F + r0 + rr] = (unsigned short)f2bfbits(so * tanhf(cc2));
    }
  } else {
    int stride = ((int)gridDim.x - 32) * 256;
    for (int i = (b - 32) * 256 + t; i < n; i += stride) deg[i] = 0;
    if (b == 32 && t == 0) *ovf_cnt = 0;
  }
}

// ---- K1: XCD-local bucket fill (blocks < NF) || xw MFMA (blocks >= NF) ----
// Fill: group g = b&7 handles only edges with (col&7)==g -> all writers of a
// bucket line share one XCD's L2 (single full-line writeback). NF=2048 gives
// 2x waves issuing atomics vs R11 (latency-hiding on the atomic round-trip).
__global__ __launch_bounds__(256) void fill_xw_kernel(
    const int* __restrict__ row, const int* __restrict__ col,
    int* __restrict__ deg, unsigned short* __restrict__ bucket,
    int* __restrict__ ovf_cnt, int* __restrict__ ovf,
    const float* __restrict__ x, const unsigned short* __restrict__ Wt,
    unsigned short* __restrict__ xwb, int n, int e) {
  int b = blockIdx.x, t = threadIdx.x;
  if (b < NF) {
    int g = b & 7;
    int cg = b >> 3;                 // 0..NF/8-1 scan-group
    const int stride = (NF / 8) * 256;
    for (int i = cg * 256 + t; i < e; i += stride) {
      int c = col[i];
      if ((c & 7) == g) {
        int r = row[i];
        int p = atomicAdd(&deg[c], 1);
        if (p < CAP) {
          bucket[(size_t)c * CAP + p] = (unsigned short)r;
        } else {
          int q = atomicAdd(ovf_cnt, 1);
          ovf[2 * q + 0] = c;
          ovf[2 * q + 1] = r;
        }
      }
    }
  } else {
    int w = t >> 6, l = t & 63;
    int q = l >> 4, m = l & 15;
    int m0 = (b - NF) * 64 + w * 16;
    int arow = m0 + m;
    bf16x8 a[4];
    const float4* xr4 = (const float4*)(x + (size_t)arow * F);
    bool rv = arow < n;
#pragma unroll
    for (int kc = 0; kc < 4; kc++) {
      uint4 pk = make_uint4(0u, 0u, 0u, 0u);
      if (rv) {
        float4 v0 = xr4[kc * 8 + q * 2 + 0];
        float4 v1 = xr4[kc * 8 + q * 2 + 1];
        pk.x = f2bfbits(v0.x) | (f2bfbits(v0.y) << 16);
        pk.y = f2bfbits(v0.z) | (f2bfbits(v0.w) << 16);
        pk.z = f2bfbits(v1.x) | (f2bfbits(v1.y) << 16);
        pk.w = f2bfbits(v1.z) | (f2bfbits(v1.w) << 16);
      }
      a[kc] = __builtin_bit_cast(bf16x8, pk);
    }
#pragma unroll
    for (int nc = 0; nc < 8; nc++) {
      f32x4 acc = {0.f, 0.f, 0.f, 0.f};
#pragma unroll
      for (int kc = 0; kc < 4; kc++) {
        uint4 bu = *(const uint4*)(Wt + (size_t)(nc * 16 + m) * F + kc * 32 + q * 8);
        acc = __builtin_amdgcn_mfma_f32_16x16x32_bf16(
            a[kc], __builtin_bit_cast(bf16x8, bu), acc, 0, 0, 0);
      }
#pragma unroll
      for (int r = 0; r < 4; r++) {
        int gr = m0 + q * 4 + r;
        if (gr < n)
          xwb[(size_t)gr * F + nc * 16 + m] = (unsigned short)f2bfbits(acc[r]);
      }
    }
  }
}

// ---- K2: pull aggregation + bias + relu + classifier (bf16 gather) --------
// Bucket line loaded as 2x uint4 (16 entries, 8 VGPR); 16-wide clamped+
// predicated gather prologue; launch_bounds(256,8) pins VGPR<=64.
__global__ __launch_bounds__(256, 8) void agg_kernel(
    const int* __restrict__ deg, const unsigned short* __restrict__ bucket,
    const unsigned int* __restrict__ xwb, const int* __restrict__ ovf_cnt,
    const int* __restrict__ ovf, const float* __restrict__ gcn_bias,
    const float* __restrict__ Wc, const float* __restrict__ bc,
    float* __restrict__ out, int n) {
  int wave = threadIdx.x >> 6;
  int lane = threadIdx.x & 63;
  int v = blockIdx.x * 4 + wave;
  if (v >= n) return;
  int d = deg[v];
  float dv = rsqrtf((float)(d + 1));  // +1 self loop, always > 0
  float ax, ay;
  {
    unsigned int u = xwb[(size_t)v * 64 + lane];  // self loop
    float sl = dv * dv;
    ax = sl * __uint_as_float(u << 16);
    ay = sl * __uint_as_float(u & 0xffff0000u);
  }
  int eend = d < CAP ? d : CAP;
  const unsigned short* bkt = bucket + (size_t)v * CAP;
  if (eend > 0) {
    // vector-load first 16 bucket entries (one 64B line, 2 requests)
    const uint4* bkt4 = (const uint4*)bkt;
    uint4 b0 = bkt4[0];
    uint4 b1 = bkt4[1];
    unsigned int bw[8] = {b0.x, b0.y, b0.z, b0.w, b1.x, b1.y, b1.z, b1.w};
    int s0 = (int)(bw[0] & 0xffffu);  // entry 0 — always valid (eend>0)
    int s[16];
#pragma unroll
    for (int q = 0; q < 16; q++) {
      int raw = (int)((bw[q >> 1] >> ((q & 1) * 16)) & 0xffffu);
      s[q] = (q < eend) ? raw : s0;  // clamp: padded slots -> valid index
    }
    unsigned int u[16];
#pragma unroll
    for (int q = 0; q < 16; q++) u[q] = xwb[(size_t)s[q] * 64 + lane];
    float nr[16];
#pragma unroll
    for (int q = 0; q < 16; q++) {
      float msk = (q < eend) ? 1.f : 0.f;
      nr[q] = rsqrtf((float)(deg[s[q]] + 1)) * dv * msk;
    }
#pragma unroll
    for (int q = 0; q < 16; q++) {
      ax = fmaf(nr[q], __uint_as_float(u[q] << 16), ax);
      ay = fmaf(nr[q], __uint_as_float(u[q] & 0xffff0000u), ay);
    }
    // 8-wide clamped loop for deg > 16 (P ~ 10%)
    for (int j = 16; j < eend; j += 8) {
      int s2[8];
      float nr2[8];
      unsigned int u2[8];
#pragma unroll
      for (int q = 0; q < 8; q++) s2[q] = bkt[j + q < eend ? j + q : 0];
#pragma unroll
      for (int q = 0; q < 8; q++) u2[q] = xwb[(size_t)s2[q] * 64 + lane];
#pragma unroll
      for (int q = 0; q < 8; q++) {
        float msk = (j + q < eend) ? 1.f : 0.f;
        nr2[q] = rsqrtf((float)(deg[s2[q]] + 1)) * dv * msk;
      }
#pragma unroll
      for (int q = 0; q < 8; q++) {
        ax = fmaf(nr2[q], __uint_as_float(u2[q] << 16), ax);
        ay = fmaf(nr2[q], __uint_as_float(u2[q] & 0xffff0000u), ay);
      }
    }
  }
  if (d > CAP) {  // correctness fallback; statistically never taken
    int oc = *ovf_cnt;
    for (int k = 0; k < oc; k++) {
      if (ovf[2 * k] == v) {
        int s = ovf[2 * k + 1];
        float nrr = rsqrtf((float)(deg[s] + 1)) * dv;
        unsigned int u = xwb[(size_t)s * 64 + lane];
        ax = fmaf(nrr, __uint_as_float(u << 16), ax);
        ay = fmaf(nrr, __uint_as_float(u & 0xffff0000u), ay);
      }
    }
  }
  int f0 = lane * 2;
  float h0 = fmaxf(ax + gcn_bias[f0], 0.f);
  float h1 = fmaxf(ay + gcn_bias[f0 + 1], 0.f);
  float a0 = h0 * Wc[f0] + h1 * Wc[f0 + 1];
  float a1 = h0 * Wc[F + f0] + h1 * Wc[F + f0 + 1];
#pragma unroll
  for (int off = 32; off > 0; off >>= 1) {
    a0 += __shfl_down(a0, off);
    a1 += __shfl_down(a1, off);
  }
  if (lane == 0) {
    out[(size_t)v * 2 + 0] = a0 + bc[0];
    out[(size_t)v * 2 + 1] = a1 + bc[1];
  }
}

extern "C" void kernel_launch(void* const* d_in, const int* in_sizes, int n_in,
                              void* d_out, int out_size, void* d_ws, size_t ws_size,
                              hipStream_t stream) {
  const float* x        = (const float*)d_in[0];
  const float* W0       = (const float*)d_in[1];
  const float* w_ih     = (const float*)d_in[2];
  // d_in[3] = w_hh unused (h0 = 0)
  const float* b_ih     = (const float*)d_in[4];
  const float* b_hh     = (const float*)d_in[5];
  const float* gcn_bias = (const float*)d_in[6];
  const float* Wc       = (const float*)d_in[7];
  const float* bc       = (const float*)d_in[8];
  const int*   ei       = (const int*)d_in[9];

  const int n = in_sizes[0] / F;   // 50000
  const int e = in_sizes[9] / 2;   // 600000
  const int* row = ei;
  const int* col = ei + e;

  // workspace layout (256 B aligned chunks)
  char* wsb = (char*)d_ws;
  unsigned short* Wt = (unsigned short*)wsb;  wsb += 32768;  // bf16 W^T
  size_t n4 = ((size_t)n * 4 + 255) & ~(size_t)255;
  int*   deg     = (int*)wsb;                 wsb += n4;     // deg[n] + ovf_cnt
  int*   ovf_cnt = deg + n;                                  // zeroed in K0
  int*   ovf     = (int*)wsb;                 wsb += 8192;   // overflow pairs
  unsigned short* bucket = (unsigned short*)wsb;
  wsb += (size_t)n * CAP * 2;                                // 3.2 MB, 64B/node
  unsigned short* xwb = (unsigned short*)wsb;                // n*128 bf16

  const int NT = (n + 63) / 64;  // 782 xw tiles

  // K0: lstm (32 blocks) || zero deg+ovf_cnt (128 blocks)
  lstm_zero_kernel<<<32 + 128, 256, 0, stream>>>(W0, w_ih, b_ih, b_hh, Wt,
                                                 deg, ovf_cnt, n);

  // K1: XCD-local single-pass bucket fill (NF blocks) || xw = x@W MFMA (NT)
  fill_xw_kernel<<<NF + NT, 256, 0, stream>>>(row, col, deg, bucket, ovf_cnt,
                                              ovf, x, Wt, xwb, n, e);

  // K2: fused pull-aggregation + bias + relu + classifier
  agg_kernel<<<(n + 3) / 4, 256, 0, stream>>>(deg, bucket,
                                              (const unsigned int*)xwb,
                                              ovf_cnt, ovf, gcn_bias, Wc, bc,
                                              (float*)d_out, n);
}

// Round 14
// 165.607 us; speedup vs baseline: 1.1749x; 1.1749x over previous
//
#include <hip/hip_runtime.h>
#include <hip/hip_bf16.h>

#define F 128
// CAP=32 u16 entries => each node's bucket is exactly ONE 64B cache line.
// E[deg]=12, P(deg>=32)~1.2e-6; overflow list keeps full correctness anyway.
// NOTE: u16 src indices require n <= 65535 (n=50000 here).
#define CAP 32
// NF=1024 measured optimum (R11: 163.4us). NF=2048 regressed (R13: 194.6us):
// col-stream L2 coalescing halved (FETCH 15.4->31.4) and fill+xw overlap broke
// (2048+782 > ~1024-block co-residency -> MFMA serialized behind fill).
#define NF 1024

typedef __bf16 bf16x8 __attribute__((ext_vector_type(8)));
typedef float f32x4 __attribute__((ext_vector_type(4)));

static __device__ __forceinline__ unsigned int f2bfbits(float f) {
  unsigned int u = __float_as_uint(f);
  return (u + 0x7fffu + ((u >> 16) & 1u)) >> 16;
}

// ---- K0: lstm (blocks 0..31) || zero deg+ovf_cnt (blocks 32..) -----------
__global__ __launch_bounds__(256) void lstm_zero_kernel(
    const float* __restrict__ W0, const float* __restrict__ w_ih,
    const float* __restrict__ b_ih, const float* __restrict__ b_hh,
    unsigned short* __restrict__ Wt, int* __restrict__ deg,
    int* __restrict__ ovf_cnt, int n) {
  __shared__ __align__(16) float srow[4][F];  // 2 KB
  __shared__ float sg[4][4 * F];              // 8 KB
  int b = blockIdx.x, t = threadIdx.x;
  if (b < 32) {
    int r0 = b * 4;
    for (int i = t; i < 4 * F; i += 256)
      srow[i >> 7][i & 127] = W0[(size_t)(r0 + (i >> 7)) * F + (i & 127)];
    __syncthreads();
#pragma unroll
    for (int half = 0; half < 2; half++) {
      int gc = t + half * 256;  // gate col 0..511
      float acc[4] = {0.f, 0.f, 0.f, 0.f};
      const float4* wv4 = (const float4*)(w_ih + (size_t)gc * F);
#pragma unroll 4
      for (int k4 = 0; k4 < F / 4; k4++) {
        float4 w = wv4[k4];
#pragma unroll
        for (int i = 0; i < 4; i++) {
          float4 s = *(const float4*)&srow[i][k4 * 4];
          acc[i] = fmaf(s.x, w.x, fmaf(s.y, w.y, fmaf(s.z, w.z, fmaf(s.w, w.w, acc[i]))));
        }
      }
      float bias = b_ih[gc] + b_hh[gc];
#pragma unroll
      for (int i = 0; i < 4; i++) sg[i][gc] = acc[i] + bias;
    }
    __syncthreads();
#pragma unroll
    for (int half = 0; half < 2; half++) {
      int idx2 = t + half * 256;  // 0..511 = 4 rows x 128 cols
      int rr = idx2 >> 7, c = idx2 & 127;
      float gi = sg[rr][c], gg = sg[rr][c + 2 * F], go = sg[rr][c + 3 * F];
      float si = 1.f / (1.f + expf(-gi));
      float so = 1.f / (1.f + expf(-go));
      float cc2 = si * tanhf(gg);
      // Wt[n][k] = bf16(W[k][n]), k = r0+rr, n = c
      Wt[(size_t)c * F + r0 + rr] = (unsigned short)f2bfbits(so * tanhf(cc2));
    }
  } else {
    int stride = ((int)gridDim.x - 32) * 256;
    for (int i = (b - 32) * 256 + t; i < n; i += stride) deg[i] = 0;
    if (b == 32 && t == 0) *ovf_cnt = 0;
  }
}

// ---- K1: XCD-local bucket fill (blocks < NF) || xw MFMA (blocks >= NF) ----
// Fill: group g = b&7 handles only edges with (col&7)==g -> all writers of a
// bucket line share one XCD's L2 (single full-line writeback). Correct for
// any block->XCD mapping; locality is best-effort.
__global__ __launch_bounds__(256) void fill_xw_kernel(
    const int* __restrict__ row, const int* __restrict__ col,
    int* __restrict__ deg, unsigned short* __restrict__ bucket,
    int* __restrict__ ovf_cnt, int* __restrict__ ovf,
    const float* __restrict__ x, const unsigned short* __restrict__ Wt,
    unsigned short* __restrict__ xwb, int n, int e) {
  int b = blockIdx.x, t = threadIdx.x;
  if (b < NF) {
    int g = b & 7;
    int cg = b >> 3;                 // 0..NF/8-1 scan-group
    const int stride = (NF / 8) * 256;
    for (int i = cg * 256 + t; i < e; i += stride) {
      int c = col[i];
      if ((c & 7) == g) {
        int r = row[i];
        int p = atomicAdd(&deg[c], 1);
        if (p < CAP) {
          bucket[(size_t)c * CAP + p] = (unsigned short)r;
        } else {
          int q = atomicAdd(ovf_cnt, 1);
          ovf[2 * q + 0] = c;
          ovf[2 * q + 1] = r;
        }
      }
    }
  } else {
    int w = t >> 6, l = t & 63;
    int q = l >> 4, m = l & 15;
    int m0 = (b - NF) * 64 + w * 16;
    int arow = m0 + m;
    bf16x8 a[4];
    const float4* xr4 = (const float4*)(x + (size_t)arow * F);
    bool rv = arow < n;
#pragma unroll
    for (int kc = 0; kc < 4; kc++) {
      uint4 pk = make_uint4(0u, 0u, 0u, 0u);
      if (rv) {
        float4 v0 = xr4[kc * 8 + q * 2 + 0];
        float4 v1 = xr4[kc * 8 + q * 2 + 1];
        pk.x = f2bfbits(v0.x) | (f2bfbits(v0.y) << 16);
        pk.y = f2bfbits(v0.z) | (f2bfbits(v0.w) << 16);
        pk.z = f2bfbits(v1.x) | (f2bfbits(v1.y) << 16);
        pk.w = f2bfbits(v1.z) | (f2bfbits(v1.w) << 16);
      }
      a[kc] = __builtin_bit_cast(bf16x8, pk);
    }
#pragma unroll
    for (int nc = 0; nc < 8; nc++) {
      f32x4 acc = {0.f, 0.f, 0.f, 0.f};
#pragma unroll
      for (int kc = 0; kc < 4; kc++) {
        uint4 bu = *(const uint4*)(Wt + (size_t)(nc * 16 + m) * F + kc * 32 + q * 8);
        acc = __builtin_amdgcn_mfma_f32_16x16x32_bf16(
            a[kc], __builtin_bit_cast(bf16x8, bu), acc, 0, 0, 0);
      }
#pragma unroll
      for (int r = 0; r < 4; r++) {
        int gr = m0 + q * 4 + r;
        if (gr < n)
          xwb[(size_t)gr * F + nc * 16 + m] = (unsigned short)f2bfbits(acc[r]);
      }
    }
  }
}

// ---- K2: pull aggregation + bias + relu + classifier (bf16 gather) --------
// Bucket line loaded as 2x uint4 (16 entries, 8 VGPR); 16-wide clamped+
// predicated gather prologue; launch_bounds(256,8) pins VGPR<=64.
__global__ __launch_bounds__(256, 8) void agg_kernel(
    const int* __restrict__ deg, const unsigned short* __restrict__ bucket,
    const unsigned int* __restrict__ xwb, const int* __restrict__ ovf_cnt,
    const int* __restrict__ ovf, const float* __restrict__ gcn_bias,
    const float* __restrict__ Wc, const float* __restrict__ bc,
    float* __restrict__ out, int n) {
  int wave = threadIdx.x >> 6;
  int lane = threadIdx.x & 63;
  int v = blockIdx.x * 4 + wave;
  if (v >= n) return;
  int d = deg[v];
  float dv = rsqrtf((float)(d + 1));  // +1 self loop, always > 0
  float ax, ay;
  {
    unsigned int u = xwb[(size_t)v * 64 + lane];  // self loop
    float sl = dv * dv;
    ax = sl * __uint_as_float(u << 16);
    ay = sl * __uint_as_float(u & 0xffff0000u);
  }
  int eend = d < CAP ? d : CAP;
  const unsigned short* bkt = bucket + (size_t)v * CAP;
  if (eend > 0) {
    // vector-load first 16 bucket entries (one 64B line, 2 requests)
    const uint4* bkt4 = (const uint4*)bkt;
    uint4 b0 = bkt4[0];
    uint4 b1 = bkt4[1];
    unsigned int bw[8] = {b0.x, b0.y, b0.z, b0.w, b1.x, b1.y, b1.z, b1.w};
    int s0 = (int)(bw[0] & 0xffffu);  // entry 0 — always valid (eend>0)
    int s[16];
#pragma unroll
    for (int q = 0; q < 16; q++) {
      int raw = (int)((bw[q >> 1] >> ((q & 1) * 16)) & 0xffffu);
      s[q] = (q < eend) ? raw : s0;  // clamp: padded slots -> valid index
    }
    unsigned int u[16];
#pragma unroll
    for (int q = 0; q < 16; q++) u[q] = xwb[(size_t)s[q] * 64 + lane];
    float nr[16];
#pragma unroll
    for (int q = 0; q < 16; q++) {
      float msk = (q < eend) ? 1.f : 0.f;
      nr[q] = rsqrtf((float)(deg[s[q]] + 1)) * dv * msk;
    }
#pragma unroll
    for (int q = 0; q < 16; q++) {
      ax = fmaf(nr[q], __uint_as_float(u[q] << 16), ax);
      ay = fmaf(nr[q], __uint_as_float(u[q] & 0xffff0000u), ay);
    }
    // 8-wide clamped loop for deg > 16 (P ~ 10%)
    for (int j = 16; j < eend; j += 8) {
      int s2[8];
      float nr2[8];
      unsigned int u2[8];
#pragma unroll
      for (int q = 0; q < 8; q++) s2[q] = bkt[j + q < eend ? j + q : 0];
#pragma unroll
      for (int q = 0; q < 8; q++) u2[q] = xwb[(size_t)s2[q] * 64 + lane];
#pragma unroll
      for (int q = 0; q < 8; q++) {
        float msk = (j + q < eend) ? 1.f : 0.f;
        nr2[q] = rsqrtf((float)(deg[s2[q]] + 1)) * dv * msk;
      }
#pragma unroll
      for (int q = 0; q < 8; q++) {
        ax = fmaf(nr2[q], __uint_as_float(u2[q] << 16), ax);
        ay = fmaf(nr2[q], __uint_as_float(u2[q] & 0xffff0000u), ay);
      }
    }
  }
  if (d > CAP) {  // correctness fallback; statistically never taken
    int oc = *ovf_cnt;
    for (int k = 0; k < oc; k++) {
      if (ovf[2 * k] == v) {
        int s = ovf[2 * k + 1];
        float nrr = rsqrtf((float)(deg[s] + 1)) * dv;
        unsigned int u = xwb[(size_t)s * 64 + lane];
        ax = fmaf(nrr, __uint_as_float(u << 16), ax);
        ay = fmaf(nrr, __uint_as_float(u & 0xffff0000u), ay);
      }
    }
  }
  int f0 = lane * 2;
  float h0 = fmaxf(ax + gcn_bias[f0], 0.f);
  float h1 = fmaxf(ay + gcn_bias[f0 + 1], 0.f);
  float a0 = h0 * Wc[f0] + h1 * Wc[f0 + 1];
  float a1 = h0 * Wc[F + f0] + h1 * Wc[F + f0 + 1];
#pragma unroll
  for (int off = 32; off > 0; off >>= 1) {
    a0 += __shfl_down(a0, off);
    a1 += __shfl_down(a1, off);
  }
  if (lane == 0) {
    out[(size_t)v * 2 + 0] = a0 + bc[0];
    out[(size_t)v * 2 + 1] = a1 + bc[1];
  }
}

extern "C" void kernel_launch(void* const* d_in, const int* in_sizes, int n_in,
                              void* d_out, int out_size, void* d_ws, size_t ws_size,
                              hipStream_t stream) {
  const float* x        = (const float*)d_in[0];
  const float* W0       = (const float*)d_in[1];
  const float* w_ih     = (const float*)d_in[2];
  // d_in[3] = w_hh unused (h0 = 0)
  const float* b_ih     = (const float*)d_in[4];
  const float* b_hh     = (const float*)d_in[5];
  const float* gcn_bias = (const float*)d_in[6];
  const float* Wc       = (const float*)d_in[7];
  const float* bc       = (const float*)d_in[8];
  const int*   ei       = (const int*)d_in[9];

  const int n = in_sizes[0] / F;   // 50000
  const int e = in_sizes[9] / 2;   // 600000
  const int* row = ei;
  const int* col = ei + e;

  // workspace layout (256 B aligned chunks)
  char* wsb = (char*)d_ws;
  unsigned short* Wt = (unsigned short*)wsb;  wsb += 32768;  // bf16 W^T
  size_t n4 = ((size_t)n * 4 + 255) & ~(size_t)255;
  int*   deg     = (int*)wsb;                 wsb += n4;     // deg[n] + ovf_cnt
  int*   ovf_cnt = deg + n;                                  // zeroed in K0
  int*   ovf     = (int*)wsb;                 wsb += 8192;   // overflow pairs
  unsigned short* bucket = (unsigned short*)wsb;
  wsb += (size_t)n * CAP * 2;                                // 3.2 MB, 64B/node
  unsigned short* xwb = (unsigned short*)wsb;                // n*128 bf16

  const int NT = (n + 63) / 64;  // 782 xw tiles

  // K0: lstm (32 blocks) || zero deg+ovf_cnt (128 blocks)
  lstm_zero_kernel<<<32 + 128, 256, 0, stream>>>(W0, w_ih, b_ih, b_hh, Wt,
                                                 deg, ovf_cnt, n);

  // K1: XCD-local single-pass bucket fill (NF blocks) || xw = x@W MFMA (NT)
  fill_xw_kernel<<<NF + NT, 256, 0, stream>>>(row, col, deg, bucket, ovf_cnt,
                                              ovf, x, Wt, xwb, n, e);

  // K2: fused pull-aggregation + bias + relu + classifier
  agg_kernel<<<(n + 3) / 4, 256, 0, stream>>>(deg, bucket,
                                              (const unsigned int*)xwb,
                                              ovf_cnt, ovf, gcn_bias, Wc, bc,
                                              (float*)d_out, n);
}